// Round 5
// baseline (8795.029 us; speedup 1.0000x reference)
//
#include <hip/hip_runtime.h>

// SCRN: 2 layers of { xp = x@Wx^T+bx ; c_t = .05c+.95xp ; h_t = tanh(c@Uc^T + h@Vh^T) } + fc.
// EMA decay 0.05 -> 16-tap filter (parallel). d = c@Uc^T parallel GEMM (stored time-major).
// Sequential part h_t = tanh(d_t + h_{t-1}@Vh^T): persistent 64-block kernel, Vh slice in LDS.
// h exchange: TAG-IN-DATA. Each h element is u32 = (tag<<16)|f16, double-buffered by step parity,
// read/written with agent-scope relaxed atomics (LLC coherence point). Valid tag == data arrived:
// NO flags, NO producer vmcnt drain, NO per-step __syncthreads (round-4 lesson: those cost 3-4
// serialized LLC round trips = 3.55us/step). Tags are monotone -> no ABA; overwrite of slot t
// requires all peers consumed t+1 (proof in round-4 notes). fp16 data, fp32 accum/tanh.

typedef _Float16 f16;
typedef _Float16 f16x8 __attribute__((ext_vector_type(8)));
typedef _Float16 f16x2 __attribute__((ext_vector_type(2)));
typedef float f32x4 __attribute__((ext_vector_type(4)));
typedef unsigned short u16;
typedef unsigned int u32;
typedef unsigned short u16x8 __attribute__((ext_vector_type(8)));
typedef unsigned long long u64;

#define DEV __device__ __forceinline__

constexpr int Tt = 512, HIDq = 512;

DEV float bf2f(u16 u) { unsigned v = ((unsigned)u) << 16; float f; __builtin_memcpy(&f, &v, 4); return f; }
DEV u16 f2bf(float f) { unsigned u; __builtin_memcpy(&u, &f, 4); u = (u + 0x7fffu + ((u >> 16) & 1u)) >> 16; return (u16)u; }
DEV float fast_tanh(float x) {
  x = fminf(30.f, fmaxf(-30.f, x));
  float e = exp2f(x * 2.885390081777927f);   // e^(2x)
  return (e - 1.f) / (e + 1.f);
}
DEV u64 al64(const u64* p) { return __hip_atomic_load(p, __ATOMIC_RELAXED, __HIP_MEMORY_SCOPE_AGENT); }
DEV void as32(u32* p, u32 v) { __hip_atomic_store(p, v, __ATOMIC_RELAXED, __HIP_MEMORY_SCOPE_AGENT); }

// ---- dtype probe: Wx0 entries bounded by 1/16; bf16 decode of f32 mantissa halves -> huge ----
__global__ void k_probe(const u16* __restrict__ w, int* __restrict__ dmode) {
  __shared__ int s;
  if (threadIdx.x == 0) s = 0;
  __syncthreads();
  int found = 0;
  for (int i = threadIdx.x; i < 8192; i += 256) {
    float v = bf2f(w[i]);
    if (fabsf(v) > 0.5f) found = 1;
  }
  if (found) atomicOr(&s, 1);
  __syncthreads();
  if (threadIdx.x == 0) *dmode = s;   // 0 = bf16 buffers, 1 = f32 buffers
}

// ---- convert n8*8 elements (bf16 or f32 per mode) -> fp16 ----
__global__ void k_cvt(const void* __restrict__ src, f16* __restrict__ dst, int n8,
                      const int* __restrict__ dmode) {
  int i = blockIdx.x * 256 + threadIdx.x;
  if (i >= n8) return;
  f16x8 o;
  if (*dmode) {
    const float4* s = (const float4*)src;
    float4 a = s[2*i], b = s[2*i+1];
    o[0]=(f16)a.x; o[1]=(f16)a.y; o[2]=(f16)a.z; o[3]=(f16)a.w;
    o[4]=(f16)b.x; o[5]=(f16)b.y; o[6]=(f16)b.z; o[7]=(f16)b.w;
  } else {
    u16x8 v = ((const u16x8*)src)[i];
#pragma unroll
    for (int j = 0; j < 8; ++j) o[j] = (f16)bf2f(v[j]);
  }
  ((f16x8*)dst)[i] = o;
}

__global__ void k_zero(u16* __restrict__ out) {  // diagnostic fallback (ws too small)
  out[blockIdx.x * 256 + threadIdx.x] = 0;
}

// ---- EMA c_t = 0.05 c_{t-1} + 0.95 xp_t ; 16-step warmup per 64-chunk ----
__global__ __launch_bounds__(128) void k_ema(const f16* __restrict__ xp, f16* __restrict__ c) {
  int b = blockIdx.x >> 3, chunk = blockIdx.x & 7;
  int t0 = chunk * 64;
  int ch = threadIdx.x;
  const f16x2* src = (const f16x2*)(xp + (size_t)b * Tt * 256) + ch;
  f16x2* dst = (f16x2*)(c + (size_t)b * Tt * 256) + ch;
  float c0 = 0.f, c1 = 0.f;
  int ts = (t0 >= 16) ? t0 - 16 : 0;
  for (int tt = ts; tt < t0 + 64; ++tt) {
    f16x2 v = src[(size_t)tt * 128];
    c0 = 0.05f * c0 + 0.95f * (float)v.x;
    c1 = 0.05f * c1 + 0.95f * (float)v.y;
    if (tt >= t0) { f16x2 o; o.x = (f16)c0; o.y = (f16)c1; dst[(size_t)tt * 128] = o; }
  }
}

// ---- GEMM: C = A[M,K] @ B[N,K]^T (+bias). TD: store C time-major (row b*512+t -> t*64+b) ----
template<bool HAS_BIAS, bool TD>
__global__ __launch_bounds__(256) void k_gemm(const f16* __restrict__ A, const f16* __restrict__ Bm,
                                              const f16* __restrict__ bias, f16* __restrict__ C,
                                              int M, int N, int K) {
  __shared__ f16 As[128][40];
  __shared__ f16 Bs[128][40];
  const int tid = threadIdx.x, lane = tid & 63, wv = tid >> 6;
  const int l15 = lane & 15, q = lane >> 4;
  const int wm = wv >> 1, wn = wv & 1;
  const int m0 = blockIdx.y * 128, n0 = blockIdx.x * 128;
  const int srow = tid >> 1, sseg = tid & 1;
  f32x4 acc[4][4] = {};
  const f16* ga = A  + (size_t)(m0 + srow) * K + sseg * 16;
  const f16* gb = Bm + (size_t)(n0 + srow) * K + sseg * 16;
  for (int k0 = 0; k0 < K; k0 += 32) {
    f16x8 a0 = *(const f16x8*)(ga + k0);
    f16x8 a1 = *(const f16x8*)(ga + k0 + 8);
    f16x8 b0 = *(const f16x8*)(gb + k0);
    f16x8 b1 = *(const f16x8*)(gb + k0 + 8);
    __syncthreads();
    *(f16x8*)&As[srow][sseg*16]     = a0;
    *(f16x8*)&As[srow][sseg*16 + 8] = a1;
    *(f16x8*)&Bs[srow][sseg*16]     = b0;
    *(f16x8*)&Bs[srow][sseg*16 + 8] = b1;
    __syncthreads();
    f16x8 af[4], bf[4];
#pragma unroll
    for (int i = 0; i < 4; ++i) af[i] = *(const f16x8*)&As[wm*64 + i*16 + l15][q*8];
#pragma unroll
    for (int i = 0; i < 4; ++i) bf[i] = *(const f16x8*)&Bs[wn*64 + i*16 + l15][q*8];
#pragma unroll
    for (int i = 0; i < 4; ++i)
#pragma unroll
      for (int j = 0; j < 4; ++j)
        acc[i][j] = __builtin_amdgcn_mfma_f32_16x16x32_f16(af[i], bf[j], acc[i][j], 0, 0, 0);
  }
#pragma unroll
  for (int j = 0; j < 4; ++j) {
    int col = n0 + wn*64 + j*16 + l15;
    float bv = HAS_BIAS ? (float)bias[col] : 0.f;
#pragma unroll
    for (int i = 0; i < 4; ++i)
#pragma unroll
      for (int r = 0; r < 4; ++r) {
        int row = m0 + wm*64 + i*16 + q*4 + r;
        size_t orow = TD ? (size_t)((row & 511) * 64 + (row >> 9)) : (size_t)row;
        C[orow * N + col] = (f16)(acc[i][j][r] + bv);
      }
  }
}

// ---- sequential recurrence: h_t = tanh(d_t + h_{t-1} @ Vh^T), tag-in-data exchange ----
// 64 blocks = 16 hid-slices(32 cols, m) x 4 batch-groups(16 rows, g); 128 thr = 2 waves.
// htag[parity][64 rows][512 cols] u32 = (tag<<16)|f16 ; h_t stored with tag t+1 in buf[t&1];
// step-t consumer expects tag==t in buf[(t-1)&1]. Chunk kk (32 cols) == producer m=kk.
__global__ __launch_bounds__(128) void k_scan(const f16* __restrict__ Vh, const f16* __restrict__ d2,
                                              u32* __restrict__ htag, f16* __restrict__ hs_out) {
  __shared__ f16 VhS[32][520];
  const int bid = blockIdx.x, m = bid & 15, g = bid >> 4;
  const int tid = threadIdx.x, wv = tid >> 6, lane = tid & 63;
  const int l15 = lane & 15, q = lane >> 4;

  // stage Vh rows 32m..32m+31 into LDS (k-contiguous)
  for (int i = tid; i < 32 * 64; i += 128) {
    int r = i >> 6, c = (i & 63) * 8;
    *(f16x8*)&VhS[r][c] = *(const f16x8*)&Vh[(size_t)(32*m + r) * HIDq + c];
  }
  // init h_{-1}=0, tag=0 into buf[1] for my 16x32 slice (no barrier needed: tags self-sync)
  for (int i = tid; i < 512; i += 128) {
    int r = i >> 5, c = i & 31;
    as32(&htag[(size_t)(64 + 16*g + r) * HIDq + 32*m + c], 0u);
  }
  __syncthreads();   // VhS ready

  for (int t = 0; t < Tt; ++t) {
    const int p = t & 1, pm1 = p ^ 1;
    // d prefetch from time-major layout: dense 64KB slab per step
    float dv[4];
    {
      const f16* dbase = d2 + ((size_t)t * 64 + 16*g + q*4) * HIDq + 32*m + 16*wv + l15;
#pragma unroll
      for (int r = 0; r < 4; ++r) dv[r] = (float)dbase[(size_t)r * HIDq];
    }
    const u32 texp = (u32)t << 16;          // expected tag (high 16) for h_{t-1}
    const u64* rowb = (const u64*)(htag + (size_t)(pm1*64 + 16*g + l15) * HIDq) + q*4;
    f32x4 acc0 = {}, acc1 = {};
    u64 cA[4], cB[4];
    // depth-2 pipelined chunk loop; chunk kk = cols kk*32+q*8..+7 (4 u64 per lane)
#pragma unroll
    for (int j = 0; j < 4; ++j) cA[j] = al64(rowb + j);
#pragma unroll
    for (int kk = 0; kk < 16; ++kk) {
      u64* cur = (kk & 1) ? cB : cA;
      u64* nxt = (kk & 1) ? cA : cB;
      if (kk < 15) {
#pragma unroll
        for (int j = 0; j < 4; ++j) nxt[j] = al64(rowb + (kk+1)*16 + j);
      }
      // validate tags of cur; retry until all 8 == texp
      for (;;) {
        u32 bad = 0;
#pragma unroll
        for (int j = 0; j < 4; ++j) {
          u32 lo = (u32)cur[j], hi = (u32)(cur[j] >> 32);
          bad |= (lo ^ texp) | (hi ^ texp);
        }
        if ((bad & 0xFFFF0000u) == 0) break;
#pragma unroll
        for (int j = 0; j < 4; ++j) cur[j] = al64(rowb + kk*16 + j);
      }
      // strip tags -> f16x8 A-fragment (k-order: low f16 from lo u32)
      union { u32 w[4]; f16x8 v; } fr;
#pragma unroll
      for (int j = 0; j < 4; ++j)
        fr.w[j] = __builtin_amdgcn_perm((u32)(cur[j] >> 32), (u32)cur[j], 0x05040100u);
      f16x8 bfr = *(const f16x8*)&VhS[16*wv + l15][kk*32 + q*8];
      if (kk & 1) acc1 = __builtin_amdgcn_mfma_f32_16x16x32_f16(fr.v, bfr, acc1, 0, 0, 0);
      else        acc0 = __builtin_amdgcn_mfma_f32_16x16x32_f16(fr.v, bfr, acc0, 0, 0, 0);
    }
    // epilogue: C layout row=q*4+r (batch), col=l15 (hid within wave slice)
    const u32 tagw = (u32)(t + 1) << 16;
    const int gcol = 32*m + 16*wv + l15;
#pragma unroll
    for (int r = 0; r < 4; ++r) {
      float z = acc0[r] + acc1[r] + dv[r];
      union { f16 h; u16 u; } cv; cv.h = (f16)fast_tanh(z);
      const int grow = 16*g + q*4 + r;
      as32(&htag[(size_t)(p*64 + grow) * HIDq + gcol], tagw | cv.u);
      if (hs_out) *(u16*)&hs_out[((size_t)grow * Tt + t) * HIDq + gcol] = cv.u;
    }
    // no barrier, no drain: tags carry the ordering
  }
}

// ---- final: out[64,128] = h_last[64,512] @ fc_w^T + fc_b; h from tagged buffer ----
__global__ __launch_bounds__(64) void k_final(const u32* __restrict__ h, const f16* __restrict__ fw,
                                              const f16* __restrict__ fb, void* __restrict__ outv,
                                              const int* __restrict__ dmode) {
  __shared__ f16 hA[16][520];
  __shared__ f16 Bw[16][520];
  const int mb = blockIdx.x & 3, nb = blockIdx.x >> 2;
  const int lane = threadIdx.x, l15 = lane & 15, q = lane >> 4;
  for (int i = lane; i < 16 * 128; i += 64) {   // tagged u32 -> f16 (low 16 bits)
    int r = i >> 7, c = (i & 127) * 4;
    uint4 v = *(const uint4*)&h[(size_t)(mb*16 + r) * 512 + c];
    union { u16 u; f16 f; } e0, e1, e2, e3;
    e0.u = (u16)v.x; e1.u = (u16)v.y; e2.u = (u16)v.z; e3.u = (u16)v.w;
    hA[r][c] = e0.f; hA[r][c+1] = e1.f; hA[r][c+2] = e2.f; hA[r][c+3] = e3.f;
  }
  for (int i = lane; i < 16 * 64; i += 64) {
    int r = i >> 6, c = (i & 63) * 8;
    *(f16x8*)&Bw[r][c] = *(const f16x8*)&fw[(size_t)(nb*16 + r) * 512 + c];
  }
  __syncthreads();
  f32x4 acc = {};
#pragma unroll
  for (int kk = 0; kk < 16; ++kk) {
    f16x8 a = *(const f16x8*)&hA[l15][kk*32 + q*8];
    f16x8 b = *(const f16x8*)&Bw[l15][kk*32 + q*8];
    acc = __builtin_amdgcn_mfma_f32_16x16x32_f16(a, b, acc, 0, 0, 0);
  }
  float bv = (float)fb[nb*16 + l15];
  int md = *dmode;
#pragma unroll
  for (int r = 0; r < 4; ++r) {
    int idx = (mb*16 + q*4 + r) * 128 + nb*16 + l15;
    float val = acc[r] + bv;
    if (md) ((float*)outv)[idx] = val;
    else    ((u16*)outv)[idx]   = f2bf(val);
  }
}

extern "C" void kernel_launch(void* const* d_in, const int* in_sizes, int n_in,
                              void* d_out, int out_size, void* d_ws, size_t ws_size,
                              hipStream_t stream) {
  if (ws_size < 88080384ull) {
    k_zero<<<32, 256, 0, stream>>>((u16*)d_out);
    return;
  }
  char* ws = (char*)d_ws;
  u32* hb1   = (u32*)(ws + 0);         // tagged h, layer 1: 2*64*512*4 = 256 KB
  u32* hb2   = (u32*)(ws + 262144);    // tagged h, layer 2: 256 KB
  int* dmode = (int*)(ws + 524288);
  f16* Wx0f = (f16*)(ws + 1048576);
  f16* Uc0f = (f16*)(ws + 1179648);
  f16* Vh0f = (f16*)(ws + 1441792);
  f16* Wx1f = (f16*)(ws + 1966080);
  f16* Uc1f = (f16*)(ws + 2228224);
  f16* Vh1f = (f16*)(ws + 2490368);
  f16* fcwf = (f16*)(ws + 3014656);
  f16* bx0f = (f16*)(ws + 3145728);
  f16* bx1f = (f16*)(ws + 3146240);
  f16* fcbf = (f16*)(ws + 3146752);
  f16* x16  = (f16*)(ws + 4194304);    // 16 MB
  f16* A    = (f16*)(ws + 20971520);   // 32 MB: db1 | xp2+cb2
  f16* Xb   = (f16*)(ws + 54525952);   // 32 MB: xp1+cb1 | hs1 | db2
  f16* xp1 = Xb;
  f16* cb1 = Xb + 8388608;
  f16* db1 = A;                        // time-major [t][b][hid]
  f16* hs1 = Xb;
  f16* xp2 = A;
  f16* cb2 = A + 8388608;
  f16* db2 = Xb;                       // time-major

  k_probe<<<1, 256, 0, stream>>>((const u16*)d_in[1], dmode);
  auto cvt = [&](const void* s, f16* d, int n) {
    int n8 = n / 8;
    k_cvt<<<dim3((n8 + 255) / 256), dim3(256), 0, stream>>>(s, d, n8, dmode);
  };
  cvt(d_in[0],  x16,  8388608);
  cvt(d_in[1],  Wx0f, 65536);
  cvt(d_in[2],  bx0f, 256);
  cvt(d_in[3],  Uc0f, 131072);
  cvt(d_in[4],  Vh0f, 262144);
  cvt(d_in[5],  Wx1f, 131072);
  cvt(d_in[6],  bx1f, 256);
  cvt(d_in[7],  Uc1f, 131072);
  cvt(d_in[8],  Vh1f, 262144);
  cvt(d_in[9],  fcwf, 65536);
  cvt(d_in[10], fcbf, 128);

  // layer 1
  k_gemm<true , false><<<dim3(2, 256), 256, 0, stream>>>(x16, Wx0f, bx0f, xp1, 32768, 256, 256);
  k_ema<<<512, 128, 0, stream>>>(xp1, cb1);
  k_gemm<false, true ><<<dim3(4, 256), 256, 0, stream>>>(cb1, Uc0f, nullptr, db1, 32768, 512, 256);
  k_scan<<<64, 128, 0, stream>>>(Vh0f, db1, hb1, hs1);
  // layer 2
  k_gemm<true , false><<<dim3(2, 256), 256, 0, stream>>>(hs1, Wx1f, bx1f, xp2, 32768, 256, 512);
  k_ema<<<512, 128, 0, stream>>>(xp2, cb2);
  k_gemm<false, true ><<<dim3(4, 256), 256, 0, stream>>>(cb2, Uc1f, nullptr, db2, 32768, 512, 256);
  k_scan<<<64, 128, 0, stream>>>(Vh1f, db2, hb2, nullptr);
  // head: h_511 (t=511 -> parity 1) in parity-1 half of hb2 (tagged)
  k_final<<<32, 64, 0, stream>>>(hb2 + 64 * 512, fcwf, fcbf, d_out, dmode);
}

// Round 6
// 3013.832 us; speedup vs baseline: 2.9182x; 2.9182x over previous
//
#include <hip/hip_runtime.h>

// SCRN: 2 layers of { xp = x@Wx^T+bx ; c_t = .05c+.95xp ; h_t = tanh(c@Uc^T + h@Vh^T) } + fc.
// EMA decay 0.05 -> 16-tap filter (parallel). d = c@Uc^T parallel GEMM (time-major). Sequential
// recurrence: 16 persistent blocks = 4 batch-groups(16 rows) x 4 hid-slices(128 cols), 256 thr.
// Vh slice REGISTER-RESIDENT (32x512 per wave = 128 VGPR); h[16][512] in LDS double buffer.
// Exchange: tagged u32 (tag<<16|f16) via agent-scope relaxed atomics; 3 peer slabs/step, all
// loads issued up front (round-5 lesson: depth-2 chunking serialized 16 LLC RTs/step; now 1).
// No flags / no drains / no global h init (poison tag 0xAAAA never matches 1..512).

typedef _Float16 f16;
typedef _Float16 f16x8 __attribute__((ext_vector_type(8)));
typedef _Float16 f16x2 __attribute__((ext_vector_type(2)));
typedef float f32x4 __attribute__((ext_vector_type(4)));
typedef unsigned short u16;
typedef unsigned int u32;
typedef unsigned short u16x8 __attribute__((ext_vector_type(8)));
typedef unsigned long long u64;

#define DEV __device__ __forceinline__

constexpr int Tt = 512, HIDq = 512;

DEV float bf2f(u16 u) { unsigned v = ((unsigned)u) << 16; float f; __builtin_memcpy(&f, &v, 4); return f; }
DEV u16 f2bf(float f) { unsigned u; __builtin_memcpy(&u, &f, 4); u = (u + 0x7fffu + ((u >> 16) & 1u)) >> 16; return (u16)u; }
DEV float fast_tanh(float x) {
  x = fminf(30.f, fmaxf(-30.f, x));
  float e = exp2f(x * 2.885390081777927f);   // e^(2x)
  return (e - 1.f) / (e + 1.f);
}
DEV u64 al64(const u64* p) { return __hip_atomic_load(p, __ATOMIC_RELAXED, __HIP_MEMORY_SCOPE_AGENT); }
DEV void as32(u32* p, u32 v) { __hip_atomic_store(p, v, __ATOMIC_RELAXED, __HIP_MEMORY_SCOPE_AGENT); }

// ---- dtype probe: Wx0 entries bounded by 1/16; bf16 decode of f32 mantissa halves -> huge ----
__global__ void k_probe(const u16* __restrict__ w, int* __restrict__ dmode) {
  __shared__ int s;
  if (threadIdx.x == 0) s = 0;
  __syncthreads();
  int found = 0;
  for (int i = threadIdx.x; i < 8192; i += 256) {
    float v = bf2f(w[i]);
    if (fabsf(v) > 0.5f) found = 1;
  }
  if (found) atomicOr(&s, 1);
  __syncthreads();
  if (threadIdx.x == 0) *dmode = s;   // 0 = bf16 buffers, 1 = f32 buffers
}

// ---- convert n8*8 elements (bf16 or f32 per mode) -> fp16 ----
__global__ void k_cvt(const void* __restrict__ src, f16* __restrict__ dst, int n8,
                      const int* __restrict__ dmode) {
  int i = blockIdx.x * 256 + threadIdx.x;
  if (i >= n8) return;
  f16x8 o;
  if (*dmode) {
    const float4* s = (const float4*)src;
    float4 a = s[2*i], b = s[2*i+1];
    o[0]=(f16)a.x; o[1]=(f16)a.y; o[2]=(f16)a.z; o[3]=(f16)a.w;
    o[4]=(f16)b.x; o[5]=(f16)b.y; o[6]=(f16)b.z; o[7]=(f16)b.w;
  } else {
    u16x8 v = ((const u16x8*)src)[i];
#pragma unroll
    for (int j = 0; j < 8; ++j) o[j] = (f16)bf2f(v[j]);
  }
  ((f16x8*)dst)[i] = o;
}

__global__ void k_zero(u16* __restrict__ out) {  // diagnostic fallback (ws too small)
  out[blockIdx.x * 256 + threadIdx.x] = 0;
}

// ---- EMA c_t = 0.05 c_{t-1} + 0.95 xp_t ; 16-step warmup per 64-chunk ----
__global__ __launch_bounds__(128) void k_ema(const f16* __restrict__ xp, f16* __restrict__ c) {
  int b = blockIdx.x >> 3, chunk = blockIdx.x & 7;
  int t0 = chunk * 64;
  int ch = threadIdx.x;
  const f16x2* src = (const f16x2*)(xp + (size_t)b * Tt * 256) + ch;
  f16x2* dst = (f16x2*)(c + (size_t)b * Tt * 256) + ch;
  float c0 = 0.f, c1 = 0.f;
  int ts = (t0 >= 16) ? t0 - 16 : 0;
  for (int tt = ts; tt < t0 + 64; ++tt) {
    f16x2 v = src[(size_t)tt * 128];
    c0 = 0.05f * c0 + 0.95f * (float)v.x;
    c1 = 0.05f * c1 + 0.95f * (float)v.y;
    if (tt >= t0) { f16x2 o; o.x = (f16)c0; o.y = (f16)c1; dst[(size_t)tt * 128] = o; }
  }
}

// ---- GEMM: C = A[M,K] @ B[N,K]^T (+bias). TD: store C time-major (row b*512+t -> t*64+b) ----
template<bool HAS_BIAS, bool TD>
__global__ __launch_bounds__(256) void k_gemm(const f16* __restrict__ A, const f16* __restrict__ Bm,
                                              const f16* __restrict__ bias, f16* __restrict__ C,
                                              int M, int N, int K) {
  __shared__ f16 As[128][40];
  __shared__ f16 Bs[128][40];
  const int tid = threadIdx.x, lane = tid & 63, wv = tid >> 6;
  const int l15 = lane & 15, q = lane >> 4;
  const int wm = wv >> 1, wn = wv & 1;
  const int m0 = blockIdx.y * 128, n0 = blockIdx.x * 128;
  const int srow = tid >> 1, sseg = tid & 1;
  f32x4 acc[4][4] = {};
  const f16* ga = A  + (size_t)(m0 + srow) * K + sseg * 16;
  const f16* gb = Bm + (size_t)(n0 + srow) * K + sseg * 16;
  for (int k0 = 0; k0 < K; k0 += 32) {
    f16x8 a0 = *(const f16x8*)(ga + k0);
    f16x8 a1 = *(const f16x8*)(ga + k0 + 8);
    f16x8 b0 = *(const f16x8*)(gb + k0);
    f16x8 b1 = *(const f16x8*)(gb + k0 + 8);
    __syncthreads();
    *(f16x8*)&As[srow][sseg*16]     = a0;
    *(f16x8*)&As[srow][sseg*16 + 8] = a1;
    *(f16x8*)&Bs[srow][sseg*16]     = b0;
    *(f16x8*)&Bs[srow][sseg*16 + 8] = b1;
    __syncthreads();
    f16x8 af[4], bf[4];
#pragma unroll
    for (int i = 0; i < 4; ++i) af[i] = *(const f16x8*)&As[wm*64 + i*16 + l15][q*8];
#pragma unroll
    for (int i = 0; i < 4; ++i) bf[i] = *(const f16x8*)&Bs[wn*64 + i*16 + l15][q*8];
#pragma unroll
    for (int i = 0; i < 4; ++i)
#pragma unroll
      for (int j = 0; j < 4; ++j)
        acc[i][j] = __builtin_amdgcn_mfma_f32_16x16x32_f16(af[i], bf[j], acc[i][j], 0, 0, 0);
  }
#pragma unroll
  for (int j = 0; j < 4; ++j) {
    int col = n0 + wn*64 + j*16 + l15;
    float bv = HAS_BIAS ? (float)bias[col] : 0.f;
#pragma unroll
    for (int i = 0; i < 4; ++i)
#pragma unroll
      for (int r = 0; r < 4; ++r) {
        int row = m0 + wm*64 + i*16 + q*4 + r;
        size_t orow = TD ? (size_t)((row & 511) * 64 + (row >> 9)) : (size_t)row;
        C[orow * N + col] = (f16)(acc[i][j][r] + bv);
      }
  }
}

// ---- sequential recurrence: h_t = tanh(d_t + h_{t-1} @ Vh^T) ----
// 16 blocks = 4 batch-groups(g: rows 16g..) x 4 hid-slices(nb: cols 128nb..); 4 waves x 64.
// Wave w: out cols 128nb+32w..+31 (2 MFMA col-tiles), Vh slice in REGISTERS (Bf[2][16]).
// hL[2][16][520]: full h row-set in LDS, double-buffered. Peers' slabs ingested via tagged
// atomic u64 loads each step; own slab published tagged, stored locally.
__global__ __launch_bounds__(256, 1) void k_scan(const f16* __restrict__ Vh,
                                                 const f16* __restrict__ d2,
                                                 u32* __restrict__ htag,
                                                 f16* __restrict__ hs_out) {
  __shared__ f16 hL[2][16][520];
  const int bid = blockIdx.x, nb = bid & 3, g = bid >> 2;
  const int tid = threadIdx.x, w = tid >> 6, lane = tid & 63;
  const int l15 = lane & 15, q = lane >> 4;
  const int colbase = 128*nb + 32*w;

  // one-time: stage Vh slice into registers (rows = out cols, k-contiguous)
  f16x8 Bf[2][16];
#pragma unroll
  for (int j = 0; j < 2; ++j)
#pragma unroll
    for (int kk = 0; kk < 16; ++kk)
      Bf[j][kk] = *(const f16x8*)&Vh[(size_t)(colbase + 16*j + l15) * HIDq + kk*32 + q*8];

  // h_{-1} = 0 in hL[0]
  for (int i = tid; i < 1024; i += 256) {
    int r = i >> 6, c = (i & 63) * 8;
    f16x8 z = {};
    *(f16x8*)&hL[0][r][c] = z;
  }
  // d_0 prefetch
  float dv[2][4];
#pragma unroll
  for (int j = 0; j < 2; ++j)
#pragma unroll
    for (int r = 0; r < 4; ++r)
      dv[j][r] = (float)d2[((size_t)0*64 + 16*g + q*4 + r) * HIDq + colbase + 16*j + l15];
  __syncthreads();

  const int irow = tid >> 4, ic8 = (tid & 15) * 8;   // ingestion element block

  for (int t = 0; t < Tt; ++t) {
    const int rb = t & 1, wb = rb ^ 1, slot = t & 1;

    // write hs for h_{t-1} (complete in hL[rb]) — coalesced b128 from LDS
    if (hs_out && t > 0) {
#pragma unroll
      for (int c = tid; c < 1024; c += 256) {
        int r = c >> 6, cc = (c & 63) * 8;
        *(f16x8*)&hs_out[((size_t)(16*g + r) * Tt + (t-1)) * HIDq + cc] =
            *(const f16x8*)&hL[rb][r][cc];
      }
    }

    // MFMA: 2 col-tiles x 16 K-chunks, A from LDS, B from registers
    f32x4 a00 = {}, a01 = {}, a10 = {}, a11 = {};
#pragma unroll
    for (int kk = 0; kk < 16; ++kk) {
      f16x8 a = *(const f16x8*)&hL[rb][l15][kk*32 + q*8];
      if (kk & 1) {
        a01 = __builtin_amdgcn_mfma_f32_16x16x32_f16(a, Bf[0][kk], a01, 0, 0, 0);
        a11 = __builtin_amdgcn_mfma_f32_16x16x32_f16(a, Bf[1][kk], a11, 0, 0, 0);
      } else {
        a00 = __builtin_amdgcn_mfma_f32_16x16x32_f16(a, Bf[0][kk], a00, 0, 0, 0);
        a10 = __builtin_amdgcn_mfma_f32_16x16x32_f16(a, Bf[1][kk], a10, 0, 0, 0);
      }
    }

    // epilogue: tanh -> publish tagged (ASAP) -> own LDS write
    const u32 tagw = (u32)(t + 1) << 16;
    u16 hbits[2][4];
#pragma unroll
    for (int j = 0; j < 2; ++j) {
      f32x4 s = j ? (a10 + a11) : (a00 + a01);
#pragma unroll
      for (int r = 0; r < 4; ++r) {
        float z = s[r] + dv[j][r];
        union { f16 h; u16 u; } cv; cv.h = (f16)fast_tanh(z);
        hbits[j][r] = cv.u;
        as32(&htag[(size_t)(slot*64 + 16*g + q*4 + r) * HIDq + colbase + 16*j + l15],
             tagw | (u32)cv.u);
      }
    }
#pragma unroll
    for (int j = 0; j < 2; ++j)
#pragma unroll
      for (int r = 0; r < 4; ++r) {
        union { u16 u; f16 h; } cv; cv.u = hbits[j][r];
        hL[wb][q*4 + r][colbase + 16*j + l15] = cv.h;
      }

    // d prefetch for t+1 (overlaps peer wait)
    if (t < Tt - 1) {
#pragma unroll
      for (int j = 0; j < 2; ++j)
#pragma unroll
        for (int r = 0; r < 4; ++r)
          dv[j][r] = (float)d2[((size_t)(t+1)*64 + 16*g + q*4 + r) * HIDq + colbase + 16*j + l15];
    }

    // ingest 3 peer slabs: issue ALL loads up front (MLP), then per-slab validate+retry
    {
      const u64* srow = (const u64*)&htag[(size_t)(slot*64 + 16*g + irow) * HIDq];
      u64 v[3][4];
#pragma unroll
      for (int s = 0; s < 3; ++s) {
        int pb = s + (s >= nb);
        const u64* pp = srow + (128*pb + ic8) / 2;
#pragma unroll
        for (int jj = 0; jj < 4; ++jj) v[s][jj] = al64(pp + jj);
      }
#pragma unroll
      for (int s = 0; s < 3; ++s) {
        int pb = s + (s >= nb);
        const u64* pp = srow + (128*pb + ic8) / 2;
        for (;;) {
          u32 bad = 0;
#pragma unroll
          for (int jj = 0; jj < 4; ++jj)
            bad |= ((u32)v[s][jj] ^ tagw) | ((u32)(v[s][jj] >> 32) ^ tagw);
          if ((bad & 0xFFFF0000u) == 0) break;
#pragma unroll
          for (int jj = 0; jj < 4; ++jj) v[s][jj] = al64(pp + jj);
        }
        union { u32 wd[4]; f16x8 vv; } fr;
#pragma unroll
        for (int jj = 0; jj < 4; ++jj)
          fr.wd[jj] = __builtin_amdgcn_perm((u32)(v[s][jj] >> 32), (u32)v[s][jj], 0x05040100u);
        *(f16x8*)&hL[wb][irow][128*pb + ic8] = fr.vv;
      }
    }
    __syncthreads();   // hL[wb] complete for step t+1
  }

  // hs for t=511 (in hL[0] = wb(511))
  if (hs_out) {
#pragma unroll
    for (int c = tid; c < 1024; c += 256) {
      int r = c >> 6, cc = (c & 63) * 8;
      *(f16x8*)&hs_out[((size_t)(16*g + r) * Tt + (Tt-1)) * HIDq + cc] =
          *(const f16x8*)&hL[0][r][cc];
    }
  }
}

// ---- final: out[64,128] = h_last[64,512] @ fc_w^T + fc_b; h from tagged buffer (atomic) ----
__global__ __launch_bounds__(64) void k_final(const u32* __restrict__ h, const f16* __restrict__ fw,
                                              const f16* __restrict__ fb, void* __restrict__ outv,
                                              const int* __restrict__ dmode) {
  __shared__ f16 hA[16][520];
  __shared__ f16 Bw[16][520];
  const int mb = blockIdx.x & 3, nb = blockIdx.x >> 2;
  const int lane = threadIdx.x, l15 = lane & 15, q = lane >> 4;
  for (int i = lane; i < 16 * 128; i += 64) {   // tagged u32 -> f16 (low 16)
    int r = i >> 7, c = (i & 127) * 4;
    const u64* p = (const u64*)&h[(size_t)(mb*16 + r) * 512 + c];
    u64 v0 = al64(p), v1 = al64(p + 1);
    *(u32*)&hA[r][c]     = __builtin_amdgcn_perm((u32)(v0 >> 32), (u32)v0, 0x05040100u);
    *(u32*)&hA[r][c + 2] = __builtin_amdgcn_perm((u32)(v1 >> 32), (u32)v1, 0x05040100u);
  }
  for (int i = lane; i < 16 * 64; i += 64) {
    int r = i >> 6, c = (i & 63) * 8;
    *(f16x8*)&Bw[r][c] = *(const f16x8*)&fw[(size_t)(nb*16 + r) * 512 + c];
  }
  __syncthreads();
  f32x4 acc = {};
#pragma unroll
  for (int kk = 0; kk < 16; ++kk) {
    f16x8 a = *(const f16x8*)&hA[l15][kk*32 + q*8];
    f16x8 b = *(const f16x8*)&Bw[l15][kk*32 + q*8];
    acc = __builtin_amdgcn_mfma_f32_16x16x32_f16(a, b, acc, 0, 0, 0);
  }
  float bv = (float)fb[nb*16 + l15];
  int md = *dmode;
#pragma unroll
  for (int r = 0; r < 4; ++r) {
    int idx = (mb*16 + q*4 + r) * 128 + nb*16 + l15;
    float val = acc[r] + bv;
    if (md) ((float*)outv)[idx] = val;
    else    ((u16*)outv)[idx]   = f2bf(val);
  }
}

extern "C" void kernel_launch(void* const* d_in, const int* in_sizes, int n_in,
                              void* d_out, int out_size, void* d_ws, size_t ws_size,
                              hipStream_t stream) {
  if (ws_size < 88080384ull) {
    k_zero<<<32, 256, 0, stream>>>((u16*)d_out);
    return;
  }
  char* ws = (char*)d_ws;
  u32* hb1   = (u32*)(ws + 0);         // tagged h, layer 1: 2*64*512*4 = 256 KB
  u32* hb2   = (u32*)(ws + 262144);    // tagged h, layer 2: 256 KB
  int* dmode = (int*)(ws + 524288);
  f16* Wx0f = (f16*)(ws + 1048576);
  f16* Uc0f = (f16*)(ws + 1179648);
  f16* Vh0f = (f16*)(ws + 1441792);
  f16* Wx1f = (f16*)(ws + 1966080);
  f16* Uc1f = (f16*)(ws + 2228224);
  f16* Vh1f = (f16*)(ws + 2490368);
  f16* fcwf = (f16*)(ws + 3014656);
  f16* bx0f = (f16*)(ws + 3145728);
  f16* bx1f = (f16*)(ws + 3146240);
  f16* fcbf = (f16*)(ws + 3146752);
  f16* x16  = (f16*)(ws + 4194304);    // 16 MB
  f16* A    = (f16*)(ws + 20971520);   // 32 MB: db1 | xp2+cb2
  f16* Xb   = (f16*)(ws + 54525952);   // 32 MB: xp1+cb1 | hs1 | db2
  f16* xp1 = Xb;
  f16* cb1 = Xb + 8388608;
  f16* db1 = A;                        // time-major [t][b][hid]
  f16* hs1 = Xb;
  f16* xp2 = A;
  f16* cb2 = A + 8388608;
  f16* db2 = Xb;                       // time-major

  k_probe<<<1, 256, 0, stream>>>((const u16*)d_in[1], dmode);
  auto cvt = [&](const void* s, f16* d, int n) {
    int n8 = n / 8;
    k_cvt<<<dim3((n8 + 255) / 256), dim3(256), 0, stream>>>(s, d, n8, dmode);
  };
  cvt(d_in[0],  x16,  8388608);
  cvt(d_in[1],  Wx0f, 65536);
  cvt(d_in[2],  bx0f, 256);
  cvt(d_in[3],  Uc0f, 131072);
  cvt(d_in[4],  Vh0f, 262144);
  cvt(d_in[5],  Wx1f, 131072);
  cvt(d_in[6],  bx1f, 256);
  cvt(d_in[7],  Uc1f, 131072);
  cvt(d_in[8],  Vh1f, 262144);
  cvt(d_in[9],  fcwf, 65536);
  cvt(d_in[10], fcbf, 128);

  // layer 1
  k_gemm<true , false><<<dim3(2, 256), 256, 0, stream>>>(x16, Wx0f, bx0f, xp1, 32768, 256, 256);
  k_ema<<<512, 128, 0, stream>>>(xp1, cb1);
  k_gemm<false, true ><<<dim3(4, 256), 256, 0, stream>>>(cb1, Uc0f, nullptr, db1, 32768, 512, 256);
  k_scan<<<16, 256, 0, stream>>>(Vh0f, db1, hb1, hs1);
  // layer 2
  k_gemm<true , false><<<dim3(2, 256), 256, 0, stream>>>(hs1, Wx1f, bx1f, xp2, 32768, 256, 512);
  k_ema<<<512, 128, 0, stream>>>(xp2, cb2);
  k_gemm<false, true ><<<dim3(4, 256), 256, 0, stream>>>(cb2, Uc1f, nullptr, db2, 32768, 512, 256);
  k_scan<<<16, 256, 0, stream>>>(Vh1f, db2, hb2, nullptr);
  // head: h_511 (t=511 -> slot 1) in slot-1 half of hb2 (tagged)
  k_final<<<32, 64, 0, stream>>>(hb2 + 64 * 512, fcwf, fcbf, d_out, dmode);
}

// Round 7
// 2826.329 us; speedup vs baseline: 3.1118x; 1.0663x over previous
//
#include <hip/hip_runtime.h>

// SCRN: 2 layers of { xp = x@Wx^T+bx ; c_t = .05c+.95xp ; h_t = tanh(c@Uc^T + h@Vh^T) } + fc.
// EMA decay 0.05 -> 16-tap filter (parallel). d = c@Uc^T parallel GEMM (time-major). Sequential
// recurrence: 8 persistent blocks = 4 batch-groups(16 rows) x 2 hid-halves(256 cols), 512 thr.
// Vh slice REGISTER-RESIDENT (32x512 per wave = 128 VGPR); h[16][512] in LDS double buffer.
// Exchange: tagged u32 (tag<<16|f16) agent-scope relaxed atomics; ONE peer slab/step, combined
// revalidation (round-6 lesson: per-slab serial retry re-paid one LLC RT per slab; community 2
// + all-at-once retry leaves publish->discover as the only serial RT). No flags, no drains.

typedef _Float16 f16;
typedef _Float16 f16x8 __attribute__((ext_vector_type(8)));
typedef _Float16 f16x2 __attribute__((ext_vector_type(2)));
typedef float f32x4 __attribute__((ext_vector_type(4)));
typedef unsigned short u16;
typedef unsigned int u32;
typedef unsigned short u16x8 __attribute__((ext_vector_type(8)));
typedef unsigned long long u64;

#define DEV __device__ __forceinline__

constexpr int Tt = 512, HIDq = 512;

DEV float bf2f(u16 u) { unsigned v = ((unsigned)u) << 16; float f; __builtin_memcpy(&f, &v, 4); return f; }
DEV u16 f2bf(float f) { unsigned u; __builtin_memcpy(&u, &f, 4); u = (u + 0x7fffu + ((u >> 16) & 1u)) >> 16; return (u16)u; }
DEV float fast_tanh(float x) {
  x = fminf(30.f, fmaxf(-30.f, x));
  float e = exp2f(x * 2.885390081777927f);   // e^(2x)
  return (e - 1.f) / (e + 1.f);
}
DEV u64 al64(const u64* p) { return __hip_atomic_load(p, __ATOMIC_RELAXED, __HIP_MEMORY_SCOPE_AGENT); }
DEV void as32(u32* p, u32 v) { __hip_atomic_store(p, v, __ATOMIC_RELAXED, __HIP_MEMORY_SCOPE_AGENT); }

// ---- dtype probe: Wx0 entries bounded by 1/16; bf16 decode of f32 mantissa halves -> huge ----
__global__ void k_probe(const u16* __restrict__ w, int* __restrict__ dmode) {
  __shared__ int s;
  if (threadIdx.x == 0) s = 0;
  __syncthreads();
  int found = 0;
  for (int i = threadIdx.x; i < 8192; i += 256) {
    float v = bf2f(w[i]);
    if (fabsf(v) > 0.5f) found = 1;
  }
  if (found) atomicOr(&s, 1);
  __syncthreads();
  if (threadIdx.x == 0) *dmode = s;   // 0 = bf16 buffers, 1 = f32 buffers
}

// ---- convert n8*8 elements (bf16 or f32 per mode) -> fp16 ----
__global__ void k_cvt(const void* __restrict__ src, f16* __restrict__ dst, int n8,
                      const int* __restrict__ dmode) {
  int i = blockIdx.x * 256 + threadIdx.x;
  if (i >= n8) return;
  f16x8 o;
  if (*dmode) {
    const float4* s = (const float4*)src;
    float4 a = s[2*i], b = s[2*i+1];
    o[0]=(f16)a.x; o[1]=(f16)a.y; o[2]=(f16)a.z; o[3]=(f16)a.w;
    o[4]=(f16)b.x; o[5]=(f16)b.y; o[6]=(f16)b.z; o[7]=(f16)b.w;
  } else {
    u16x8 v = ((const u16x8*)src)[i];
#pragma unroll
    for (int j = 0; j < 8; ++j) o[j] = (f16)bf2f(v[j]);
  }
  ((f16x8*)dst)[i] = o;
}

__global__ void k_zero(u16* __restrict__ out) {  // diagnostic fallback (ws too small)
  out[blockIdx.x * 256 + threadIdx.x] = 0;
}

// ---- EMA c_t = 0.05 c_{t-1} + 0.95 xp_t ; 16-step warmup per 64-chunk ----
__global__ __launch_bounds__(128) void k_ema(const f16* __restrict__ xp, f16* __restrict__ c) {
  int b = blockIdx.x >> 3, chunk = blockIdx.x & 7;
  int t0 = chunk * 64;
  int ch = threadIdx.x;
  const f16x2* src = (const f16x2*)(xp + (size_t)b * Tt * 256) + ch;
  f16x2* dst = (f16x2*)(c + (size_t)b * Tt * 256) + ch;
  float c0 = 0.f, c1 = 0.f;
  int ts = (t0 >= 16) ? t0 - 16 : 0;
  for (int tt = ts; tt < t0 + 64; ++tt) {
    f16x2 v = src[(size_t)tt * 128];
    c0 = 0.05f * c0 + 0.95f * (float)v.x;
    c1 = 0.05f * c1 + 0.95f * (float)v.y;
    if (tt >= t0) { f16x2 o; o.x = (f16)c0; o.y = (f16)c1; dst[(size_t)tt * 128] = o; }
  }
}

// ---- GEMM: C = A[M,K] @ B[N,K]^T (+bias). TD: store C time-major (row b*512+t -> t*64+b) ----
template<bool HAS_BIAS, bool TD>
__global__ __launch_bounds__(256) void k_gemm(const f16* __restrict__ A, const f16* __restrict__ Bm,
                                              const f16* __restrict__ bias, f16* __restrict__ C,
                                              int M, int N, int K) {
  __shared__ f16 As[128][40];
  __shared__ f16 Bs[128][40];
  const int tid = threadIdx.x, lane = tid & 63, wv = tid >> 6;
  const int l15 = lane & 15, q = lane >> 4;
  const int wm = wv >> 1, wn = wv & 1;
  const int m0 = blockIdx.y * 128, n0 = blockIdx.x * 128;
  const int srow = tid >> 1, sseg = tid & 1;
  f32x4 acc[4][4] = {};
  const f16* ga = A  + (size_t)(m0 + srow) * K + sseg * 16;
  const f16* gb = Bm + (size_t)(n0 + srow) * K + sseg * 16;
  for (int k0 = 0; k0 < K; k0 += 32) {
    f16x8 a0 = *(const f16x8*)(ga + k0);
    f16x8 a1 = *(const f16x8*)(ga + k0 + 8);
    f16x8 b0 = *(const f16x8*)(gb + k0);
    f16x8 b1 = *(const f16x8*)(gb + k0 + 8);
    __syncthreads();
    *(f16x8*)&As[srow][sseg*16]     = a0;
    *(f16x8*)&As[srow][sseg*16 + 8] = a1;
    *(f16x8*)&Bs[srow][sseg*16]     = b0;
    *(f16x8*)&Bs[srow][sseg*16 + 8] = b1;
    __syncthreads();
    f16x8 af[4], bf[4];
#pragma unroll
    for (int i = 0; i < 4; ++i) af[i] = *(const f16x8*)&As[wm*64 + i*16 + l15][q*8];
#pragma unroll
    for (int i = 0; i < 4; ++i) bf[i] = *(const f16x8*)&Bs[wn*64 + i*16 + l15][q*8];
#pragma unroll
    for (int i = 0; i < 4; ++i)
#pragma unroll
      for (int j = 0; j < 4; ++j)
        acc[i][j] = __builtin_amdgcn_mfma_f32_16x16x32_f16(af[i], bf[j], acc[i][j], 0, 0, 0);
  }
#pragma unroll
  for (int j = 0; j < 4; ++j) {
    int col = n0 + wn*64 + j*16 + l15;
    float bv = HAS_BIAS ? (float)bias[col] : 0.f;
#pragma unroll
    for (int i = 0; i < 4; ++i)
#pragma unroll
      for (int r = 0; r < 4; ++r) {
        int row = m0 + wm*64 + i*16 + q*4 + r;
        size_t orow = TD ? (size_t)((row & 511) * 64 + (row >> 9)) : (size_t)row;
        C[orow * N + col] = (f16)(acc[i][j][r] + bv);
      }
  }
}

// ---- sequential recurrence: h_t = tanh(d_t + h_{t-1} @ Vh^T) ----
// 8 blocks = 4 batch-groups(g: rows 16g..) x 2 hid-halves(hf: cols 256hf..); 8 waves x 64.
// Wave w: out cols 256hf+32w..+31 (2 MFMA col-tiles), Vh slice in REGISTERS (Bf[2][16]).
// hL[2][16][520]: full h row-set in LDS, double-buffered. ONE peer slab (16x256) ingested per
// step via tagged atomic u64 loads with combined revalidation; own slab published tagged.
__global__ __launch_bounds__(512, 2) void k_scan(const f16* __restrict__ Vh,
                                                 const f16* __restrict__ d2,
                                                 u32* __restrict__ htag,
                                                 f16* __restrict__ hs_out) {
  __shared__ f16 hL[2][16][520];
  const int bid = blockIdx.x, hf = bid & 1, g = bid >> 1;
  const int tid = threadIdx.x, w = tid >> 6, lane = tid & 63;
  const int l15 = lane & 15, q = lane >> 4;
  const int colbase = 256*hf + 32*w;

  // one-time: stage Vh slice into registers (rows = out cols, k-contiguous)
  f16x8 Bf[2][16];
#pragma unroll
  for (int j = 0; j < 2; ++j)
#pragma unroll
    for (int kk = 0; kk < 16; ++kk)
      Bf[j][kk] = *(const f16x8*)&Vh[(size_t)(colbase + 16*j + l15) * HIDq + kk*32 + q*8];

  // h_{-1} = 0 in hL[0]
  for (int i = tid; i < 1024; i += 512) {
    int r = i >> 6, c = (i & 63) * 8;
    f16x8 z = {};
    *(f16x8*)&hL[0][r][c] = z;
  }
  // d_0 prefetch
  float dv[2][4];
#pragma unroll
  for (int j = 0; j < 2; ++j)
#pragma unroll
    for (int r = 0; r < 4; ++r)
      dv[j][r] = (float)d2[((size_t)0*64 + 16*g + q*4 + r) * HIDq + colbase + 16*j + l15];
  __syncthreads();

  const int irow = tid >> 5, ic8 = (tid & 31) * 8;   // peer-slab ingest: 16 rows x 256 cols
  const int pcol = 256*(hf ^ 1) + ic8;

  for (int t = 0; t < Tt; ++t) {
    const int rb = t & 1, wb = rb ^ 1, slot = t & 1;

    // write hs for h_{t-1} (complete in hL[rb]) — coalesced b128 from LDS, fire-and-forget
    if (hs_out && t > 0) {
#pragma unroll
      for (int c = tid; c < 1024; c += 512) {
        int r = c >> 6, cc = (c & 63) * 8;
        *(f16x8*)&hs_out[((size_t)(16*g + r) * Tt + (t-1)) * HIDq + cc] =
            *(const f16x8*)&hL[rb][r][cc];
      }
    }

    // MFMA: 2 col-tiles x 16 K-chunks, A from LDS, B from registers (4 indep acc chains)
    f32x4 a00 = {}, a01 = {}, a10 = {}, a11 = {};
#pragma unroll
    for (int kk = 0; kk < 16; ++kk) {
      f16x8 a = *(const f16x8*)&hL[rb][l15][kk*32 + q*8];
      if (kk & 1) {
        a01 = __builtin_amdgcn_mfma_f32_16x16x32_f16(a, Bf[0][kk], a01, 0, 0, 0);
        a11 = __builtin_amdgcn_mfma_f32_16x16x32_f16(a, Bf[1][kk], a11, 0, 0, 0);
      } else {
        a00 = __builtin_amdgcn_mfma_f32_16x16x32_f16(a, Bf[0][kk], a00, 0, 0, 0);
        a10 = __builtin_amdgcn_mfma_f32_16x16x32_f16(a, Bf[1][kk], a10, 0, 0, 0);
      }
    }

    // epilogue: tanh -> publish tagged ASAP -> own LDS write
    const u32 tagw = (u32)(t + 1) << 16;
    u16 hbits[2][4];
#pragma unroll
    for (int j = 0; j < 2; ++j) {
      f32x4 s = j ? (a10 + a11) : (a00 + a01);
#pragma unroll
      for (int r = 0; r < 4; ++r) {
        float z = s[r] + dv[j][r];
        union { f16 h; u16 u; } cv; cv.h = (f16)fast_tanh(z);
        hbits[j][r] = cv.u;
        as32(&htag[(size_t)(slot*64 + 16*g + q*4 + r) * HIDq + colbase + 16*j + l15],
             tagw | (u32)cv.u);
      }
    }
#pragma unroll
    for (int j = 0; j < 2; ++j)
#pragma unroll
      for (int r = 0; r < 4; ++r) {
        union { u16 u; f16 h; } cv; cv.u = hbits[j][r];
        hL[wb][q*4 + r][colbase + 16*j + l15] = cv.h;
      }

    // d prefetch for t+1 (overlaps peer wait)
    if (t < Tt - 1) {
#pragma unroll
      for (int j = 0; j < 2; ++j)
#pragma unroll
        for (int r = 0; r < 4; ++r)
          dv[j][r] = (float)d2[((size_t)(t+1)*64 + 16*g + q*4 + r) * HIDq + colbase + 16*j + l15];
    }

    // ingest peer slab (4 u64/thread): combined load + combined revalidation (no serial RTs)
    {
      const u64* pp = (const u64*)&htag[(size_t)(slot*64 + 16*g + irow) * HIDq] + pcol/2;
      u64 v[4];
#pragma unroll
      for (int jj = 0; jj < 4; ++jj) v[jj] = al64(pp + jj);
      for (;;) {
        u32 bad = 0;
#pragma unroll
        for (int jj = 0; jj < 4; ++jj)
          bad |= ((u32)v[jj] ^ tagw) | ((u32)(v[jj] >> 32) ^ tagw);
        if ((bad & 0xFFFF0000u) == 0) break;
#pragma unroll
        for (int jj = 0; jj < 4; ++jj) v[jj] = al64(pp + jj);
      }
      union { u32 wd[4]; f16x8 vv; } fr;
#pragma unroll
      for (int jj = 0; jj < 4; ++jj)
        fr.wd[jj] = __builtin_amdgcn_perm((u32)(v[jj] >> 32), (u32)v[jj], 0x05040100u);
      *(f16x8*)&hL[wb][irow][pcol] = fr.vv;
    }
    __syncthreads();   // hL[wb] complete for step t+1
  }

  // hs for t=511 (in hL[0] = wb(511))
  if (hs_out) {
#pragma unroll
    for (int c = tid; c < 1024; c += 512) {
      int r = c >> 6, cc = (c & 63) * 8;
      *(f16x8*)&hs_out[((size_t)(16*g + r) * Tt + (Tt-1)) * HIDq + cc] =
          *(const f16x8*)&hL[0][r][cc];
    }
  }
}

// ---- final: out[64,128] = h_last[64,512] @ fc_w^T + fc_b; h from tagged buffer (atomic) ----
__global__ __launch_bounds__(64) void k_final(const u32* __restrict__ h, const f16* __restrict__ fw,
                                              const f16* __restrict__ fb, void* __restrict__ outv,
                                              const int* __restrict__ dmode) {
  __shared__ f16 hA[16][520];
  __shared__ f16 Bw[16][520];
  const int mb = blockIdx.x & 3, nb = blockIdx.x >> 2;
  const int lane = threadIdx.x, l15 = lane & 15, q = lane >> 4;
  for (int i = lane; i < 16 * 128; i += 64) {   // tagged u32 -> f16 (low 16)
    int r = i >> 7, c = (i & 127) * 4;
    const u64* p = (const u64*)&h[(size_t)(mb*16 + r) * 512 + c];
    u64 v0 = al64(p), v1 = al64(p + 1);
    *(u32*)&hA[r][c]     = __builtin_amdgcn_perm((u32)(v0 >> 32), (u32)v0, 0x05040100u);
    *(u32*)&hA[r][c + 2] = __builtin_amdgcn_perm((u32)(v1 >> 32), (u32)v1, 0x05040100u);
  }
  for (int i = lane; i < 16 * 64; i += 64) {
    int r = i >> 6, c = (i & 63) * 8;
    *(f16x8*)&Bw[r][c] = *(const f16x8*)&fw[(size_t)(nb*16 + r) * 512 + c];
  }
  __syncthreads();
  f32x4 acc = {};
#pragma unroll
  for (int kk = 0; kk < 16; ++kk) {
    f16x8 a = *(const f16x8*)&hA[l15][kk*32 + q*8];
    f16x8 b = *(const f16x8*)&Bw[l15][kk*32 + q*8];
    acc = __builtin_amdgcn_mfma_f32_16x16x32_f16(a, b, acc, 0, 0, 0);
  }
  float bv = (float)fb[nb*16 + l15];
  int md = *dmode;
#pragma unroll
  for (int r = 0; r < 4; ++r) {
    int idx = (mb*16 + q*4 + r) * 128 + nb*16 + l15;
    float val = acc[r] + bv;
    if (md) ((float*)outv)[idx] = val;
    else    ((u16*)outv)[idx]   = f2bf(val);
  }
}

extern "C" void kernel_launch(void* const* d_in, const int* in_sizes, int n_in,
                              void* d_out, int out_size, void* d_ws, size_t ws_size,
                              hipStream_t stream) {
  if (ws_size < 88080384ull) {
    k_zero<<<32, 256, 0, stream>>>((u16*)d_out);
    return;
  }
  char* ws = (char*)d_ws;
  u32* hb1   = (u32*)(ws + 0);         // tagged h, layer 1: 2*64*512*4 = 256 KB
  u32* hb2   = (u32*)(ws + 262144);    // tagged h, layer 2: 256 KB
  int* dmode = (int*)(ws + 524288);
  f16* Wx0f = (f16*)(ws + 1048576);
  f16* Uc0f = (f16*)(ws + 1179648);
  f16* Vh0f = (f16*)(ws + 1441792);
  f16* Wx1f = (f16*)(ws + 1966080);
  f16* Uc1f = (f16*)(ws + 2228224);
  f16* Vh1f = (f16*)(ws + 2490368);
  f16* fcwf = (f16*)(ws + 3014656);
  f16* bx0f = (f16*)(ws + 3145728);
  f16* bx1f = (f16*)(ws + 3146240);
  f16* fcbf = (f16*)(ws + 3146752);
  f16* x16  = (f16*)(ws + 4194304);    // 16 MB
  f16* A    = (f16*)(ws + 20971520);   // 32 MB: db1 | xp2+cb2
  f16* Xb   = (f16*)(ws + 54525952);   // 32 MB: xp1+cb1 | hs1 | db2
  f16* xp1 = Xb;
  f16* cb1 = Xb + 8388608;
  f16* db1 = A;                        // time-major [t][b][hid]
  f16* hs1 = Xb;
  f16* xp2 = A;
  f16* cb2 = A + 8388608;
  f16* db2 = Xb;                       // time-major

  k_probe<<<1, 256, 0, stream>>>((const u16*)d_in[1], dmode);
  auto cvt = [&](const void* s, f16* d, int n) {
    int n8 = n / 8;
    k_cvt<<<dim3((n8 + 255) / 256), dim3(256), 0, stream>>>(s, d, n8, dmode);
  };
  cvt(d_in[0],  x16,  8388608);
  cvt(d_in[1],  Wx0f, 65536);
  cvt(d_in[2],  bx0f, 256);
  cvt(d_in[3],  Uc0f, 131072);
  cvt(d_in[4],  Vh0f, 262144);
  cvt(d_in[5],  Wx1f, 131072);
  cvt(d_in[6],  bx1f, 256);
  cvt(d_in[7],  Uc1f, 131072);
  cvt(d_in[8],  Vh1f, 262144);
  cvt(d_in[9],  fcwf, 65536);
  cvt(d_in[10], fcbf, 128);

  // layer 1
  k_gemm<true , false><<<dim3(2, 256), 256, 0, stream>>>(x16, Wx0f, bx0f, xp1, 32768, 256, 256);
  k_ema<<<512, 128, 0, stream>>>(xp1, cb1);
  k_gemm<false, true ><<<dim3(4, 256), 256, 0, stream>>>(cb1, Uc0f, nullptr, db1, 32768, 512, 256);
  k_scan<<<8, 512, 0, stream>>>(Vh0f, db1, hb1, hs1);
  // layer 2
  k_gemm<true , false><<<dim3(2, 256), 256, 0, stream>>>(hs1, Wx1f, bx1f, xp2, 32768, 256, 512);
  k_ema<<<512, 128, 0, stream>>>(xp2, cb2);
  k_gemm<false, true ><<<dim3(4, 256), 256, 0, stream>>>(cb2, Uc1f, nullptr, db2, 32768, 512, 256);
  k_scan<<<8, 512, 0, stream>>>(Vh1f, db2, hb2, nullptr);
  // head: h_511 (t=511 -> slot 1) in slot-1 half of hb2 (tagged)
  k_final<<<32, 64, 0, stream>>>(hb2 + 64 * 512, fcwf, fcbf, d_out, dmode);
}